// Round 12
// baseline (104.408 us; speedup 1.0000x reference)
//
#include <hip/hip_runtime.h>
#include <hip/hip_bf16.h>
#include <cstdint>

#define BATCH 8192
#define DIM   128
#define KAUG  160          // 128 data + 10 label dims + 22 zero pad
#define MARGIN 1.0f
#define SEP    8192.0f     // 2 * 64^2 label separator (exact in fp32/bf16)

typedef __attribute__((ext_vector_type(8))) short short8;
typedef __attribute__((ext_vector_type(4))) float f32x4;

// async 16B global -> LDS; LDS dst = wave-uniform base, HW adds lane*16
__device__ __forceinline__ void async_copy16(const void* g, void* lds) {
    __builtin_amdgcn_global_load_lds(
        (const __attribute__((address_space(1))) unsigned int*)g,
        (__attribute__((address_space(3))) unsigned int*)lds, 16, 0, 0);
}

// ---------------------------------------------------------------------------
// Kernel 1: build label-AUGMENTED bf16 matrices (validated R10/R11, absmax 0):
//   EbfA row i: [bf16(e_i), +64*onehot(lab_i), 0...]   (160 dims)
//   EbfB row j: [bf16(e_j), -64*onehot(lab_j), 0...]
//   val = sq_col - 2*dot_aug = (sq_col - 2*dot) + 8192*[same]: label
//   selection is pure max/min (3 VALU/pair, no label loads in the GEMM).
// ---------------------------------------------------------------------------
__global__ __launch_bounds__(256) void bhtl_prep(
    const float* __restrict__ emb,
    const int* __restrict__ labels,
    __hip_bfloat16* __restrict__ EbfA,
    __hip_bfloat16* __restrict__ EbfB,
    float* __restrict__ sq,
    unsigned* __restrict__ hp2,
    unsigned* __restrict__ hn2)
{
    const int w   = threadIdx.x >> 6;
    const int l   = threadIdx.x & 63;
    const int row = blockIdx.x * 4 + w;
    const float2 e = ((const float2*)(emb + row * DIM))[l];
    __hip_bfloat162 h2;
    h2.x = __float2bfloat16(e.x);
    h2.y = __float2bfloat16(e.y);
    ((__hip_bfloat162*)(EbfA + (size_t)row * KAUG))[l] = h2;
    ((__hip_bfloat162*)(EbfB + (size_t)row * KAUG))[l] = h2;
    if (l < 16) {   // augmented dims 128 + 2l, 129 + 2l
        const int lab = labels[row];
        const float a0 = (2 * l     == lab) ? 64.f : 0.f;
        const float a1 = (2 * l + 1 == lab) ? 64.f : 0.f;
        __hip_bfloat162 hA, hB;
        hA.x = __float2bfloat16(a0);  hA.y = __float2bfloat16(a1);
        hB.x = __float2bfloat16(-a0); hB.y = __float2bfloat16(-a1);
        ((__hip_bfloat162*)(EbfA + (size_t)row * KAUG + DIM))[l] = hA;
        ((__hip_bfloat162*)(EbfB + (size_t)row * KAUG + DIM))[l] = hB;
    }
    float s = e.x * e.x + e.y * e.y;
    #pragma unroll
    for (int d = 1; d < 64; d <<= 1) s += __shfl_xor(s, d, 64);
    if (l == 0) {
        sq[row]  = s;
        hp2[row] = 0u;           // max accumulator (clamped non-negative)
        hn2[row] = 0x7F800000u;  // +inf (min accumulator)
    }
}

// ---------------------------------------------------------------------------
// Kernel 2: TRIANGLE fused GEMM + hardest-pos/neg (d(i,j)=d(j,i): compute
// only tile pairs rt <= ct -> 2080 of 4096 tiles; halves MFMA/ds_read/stage).
//   2080 blocks, 128 threads (2 waves). Tile: 128 rows (rt) x 128 cols (ct).
//   B tile (128 cols x 320 B = 40 KB) staged ONCE via glds (40 instrs),
//   one __syncthreads, then 8 chunks of 16 cols — whole tile LDS-resident,
//   no dbuf/pipelining needed.
//   Row side (every block): val_r = fmaf(-2, acc, sq_col); mp/mn as R10.
//   Col side (rt != ct only): val_c = fmaf(-2, acc, sqi[m]); in-lane
//   m-reduce (4->1), ln-shuffle-reduce (16 lanes), wave-private LDS stripe
//   write (each (wave,col) written exactly once across the 8 chunks);
//   end barrier, stripe combine, atomics. Covers pair (j,i) for tiles
//   rt<ct without ever visiting block (ct,rt).
// XOR swizzle (validated R6-R11) on the global side; transposed MFMA
//   (validated R4-R11): lane(q,ln) elem r -> row=+m*16+ln, col=+q*4+r.
// LDS 43 KB -> 3 blocks/CU. Atomics fire-and-forget, NO fence (R5 lesson).
// ---------------------------------------------------------------------------
__global__ __launch_bounds__(128) void bhtl_main(
    const __hip_bfloat16* __restrict__ EbfA,
    const __hip_bfloat16* __restrict__ EbfB,
    const float* __restrict__ sq,
    unsigned* __restrict__ hp2,
    unsigned* __restrict__ hn2)
{
    __shared__ __align__(16) unsigned short B_s[20480];   // 2560 units x 16 B
    __shared__ __align__(16) float sqm[256];              // col sq (over-staged)
    __shared__ float cmaxS[2][128];                       // per-wave col stripes
    __shared__ float cminS[2][128];

    const int tid  = threadIdx.x;
    const int w    = tid >> 6;
    const int lane = tid & 63;
    const int q    = lane >> 4;
    const int ln   = lane & 15;

    // ---- triangular decode: bid -> (rt, ct), rt <= ct, T(r) = r(129-r)/2 ----
    const int bid = blockIdx.x;
    int rt = (int)floorf((129.0f - sqrtf(16641.0f - 8.0f * (float)bid)) * 0.5f);
    {   // fp32 edge fixup
        int Tr = (rt * (129 - rt)) >> 1;
        int Tn = ((rt + 1) * (128 - rt)) >> 1;
        if (bid < Tr)      rt -= 1;
        else if (bid >= Tn) rt += 1;
    }
    const int Trt = (rt * (129 - rt)) >> 1;
    const int ct  = rt + (bid - Trt);
    const bool offd = (rt != ct);
    const int rowbase = rt * 128 + w * 64;
    const int colbase = ct * 128;

    // ---- stage B tile: 2560 units; wave w -> units [w*1280, +1280) ----
    #pragma unroll
    for (int c = 0; c < 20; ++c) {
        int U   = w * 1280 + c * 64 + lane;
        int col = U / 20;                       // 0..127 (magic-mul)
        int u   = U - col * 20;                 // 0..19
        int g   = (u < 16) ? (u ^ (col & 7)) : u;   // global-side swizzle
        async_copy16(EbfB + (size_t)(colbase + col) * KAUG + g * 8,
                     &B_s[(w * 1280 + c * 64) * 8]);
    }
    // col sq: 128 floats; all 64 lanes stage (dup into sqm[128..255], unused)
    if (w == 0)
        async_copy16(sq + colbase + (lane & 31) * 4, &sqm[0]);

    // ---- A fragments (64 rows/wave, K=160) + row sq ----
    short8 af[4][5];
    float  sqi[4];
    #pragma unroll
    for (int m = 0; m < 4; ++m) {
        const int row = rowbase + m * 16 + ln;
        #pragma unroll
        for (int kc = 0; kc < 5; ++kc) {
            af[m][kc] = *(const short8*)(EbfA + (size_t)row * KAUG + kc * 32 + q * 8);
            asm("" : "+v"(af[m][kc]));
        }
        sqi[m] = sq[row];
    }

    __syncthreads();   // drains glds (vmcnt) + barrier: B tile + sqm ready

    float mp[4] = {-INFINITY, -INFINITY, -INFINITY, -INFINITY};
    float mn[4] = { INFINITY,  INFINITY,  INFINITY,  INFINITY};

    #pragma unroll 2
    for (int ch = 0; ch < 8; ++ch) {
        // fragments for 16 cols (first-operand layout: col = ch*16 + ln)
        short8 bfr[5];
        #pragma unroll
        for (int kc = 0; kc < 5; ++kc) {
            const int t    = kc * 4 + q;
            const int unit = (t < 16) ? (t ^ (ln & 7)) : t;
            bfr[kc] = *(const short8*)(&B_s[((ch * 16 + ln) * 20 + unit) * 8]);
        }
        f32x4 sqj = *(const f32x4*)(&sqm[ch * 16 + q * 4]);

        f32x4 acc[4];
        const f32x4 zero = {0.f, 0.f, 0.f, 0.f};
        #pragma unroll
        for (int m = 0; m < 4; ++m) acc[m] = zero;
        #pragma unroll
        for (int kc = 0; kc < 5; ++kc)
            #pragma unroll
            for (int m = 0; m < 4; ++m)
                acc[m] = __builtin_amdgcn_mfma_f32_16x16x32_bf16(
                    bfr[kc], af[m][kc], acc[m], 0, 0, 0);   // transposed

        // ---- row-side epilogue (3 VALU/pair) ----
        #pragma unroll
        for (int m = 0; m < 4; ++m)
            #pragma unroll
            for (int r = 0; r < 4; ++r) {
                float val = fmaf(-2.0f, acc[m][r], sqj[r]);
                mp[m] = fmaxf(mp[m], val);
                mn[m] = fminf(mn[m], val);
            }

        // ---- col-side epilogue (off-diagonal only) ----
        if (offd) {
            float cmx[4], cmn[4];
            #pragma unroll
            for (int r = 0; r < 4; ++r) {
                float v0 = fmaf(-2.0f, acc[0][r], sqi[0]);
                float v1 = fmaf(-2.0f, acc[1][r], sqi[1]);
                float v2 = fmaf(-2.0f, acc[2][r], sqi[2]);
                float v3 = fmaf(-2.0f, acc[3][r], sqi[3]);
                cmx[r] = fmaxf(fmaxf(v0, v1), fmaxf(v2, v3));
                cmn[r] = fminf(fminf(v0, v1), fminf(v2, v3));
            }
            #pragma unroll
            for (int r = 0; r < 4; ++r)
                #pragma unroll
                for (int d = 1; d < 16; d <<= 1) {
                    cmx[r] = fmaxf(cmx[r], __shfl_xor(cmx[r], d, 64));
                    cmn[r] = fminf(cmn[r], __shfl_xor(cmn[r], d, 64));
                }
            if (ln == 0) {      // 4 lanes (q), each writes 4 distinct cols
                #pragma unroll
                for (int r = 0; r < 4; ++r) {
                    cmaxS[w][ch * 16 + q * 4 + r] = cmx[r];
                    cminS[w][ch * 16 + q * 4 + r] = cmn[r];
                }
            }
        }
    }

    // ---- row-side q-reduce into registers (shuffles only, pre-barrier) ----
    float rhp[4], rhn[4];
    #pragma unroll
    for (int m = 0; m < 4; ++m) {
        float a = mp[m], b = mn[m];
        a = fmaxf(a, __shfl_xor(a, 16, 64));
        a = fmaxf(a, __shfl_xor(a, 32, 64));
        b = fminf(b, __shfl_xor(b, 16, 64));
        b = fminf(b, __shfl_xor(b, 32, 64));
        rhp[m] = fmaxf(sqi[m] + a - SEP, 0.0f);   // clamp: uint order == float
        rhn[m] = fmaxf(sqi[m] + b, 0.0f);
    }

    __syncthreads();   // stripes visible (lgkmcnt drained by syncthreads)

    // ---- col-side combine + atomics (off-diagonal) ----
    if (offd) {
        const int ccol = tid;                   // 0..127
        float a  = fmaxf(cmaxS[0][ccol], cmaxS[1][ccol]);
        float b  = fminf(cminS[0][ccol], cminS[1][ccol]);
        float sj = sqm[ccol];
        atomicMax(&hp2[colbase + ccol], __float_as_uint(fmaxf(sj + a - SEP, 0.0f)));
        atomicMin(&hn2[colbase + ccol], __float_as_uint(fmaxf(sj + b, 0.0f)));
    }

    // ---- row-side atomics ----
    #pragma unroll
    for (int m = 0; m < 4; ++m)
        if (q == 0) {
            const int row = rowbase + m * 16 + ln;
            atomicMax(&hp2[row], __float_as_uint(rhp[m]));
            atomicMin(&hn2[row], __float_as_uint(rhn[m]));
        }
}

// ---------------------------------------------------------------------------
// Kernel 3: per-anchor loss + mean. Single block, deterministic output.
// ---------------------------------------------------------------------------
__global__ __launch_bounds__(1024) void bhtl_final(
    const unsigned* __restrict__ hp2,
    const unsigned* __restrict__ hn2,
    float* __restrict__ out)
{
    __shared__ float red[16];
    float sum = 0.f;
    for (int i = threadIdx.x; i < BATCH; i += 1024) {
        float hp = sqrtf(__uint_as_float(hp2[i]));
        float hn = sqrtf(__uint_as_float(hn2[i]));
        sum += fmaxf(hp - hn + MARGIN, 0.f);
    }
    #pragma unroll
    for (int d = 1; d < 64; d <<= 1) sum += __shfl_xor(sum, d, 64);
    int wv = threadIdx.x >> 6;
    if ((threadIdx.x & 63) == 0) red[wv] = sum;
    __syncthreads();
    if (threadIdx.x < 64) {
        float v = (threadIdx.x < 16) ? red[threadIdx.x] : 0.f;
        #pragma unroll
        for (int d = 1; d < 16; d <<= 1) v += __shfl_xor(v, d, 64);
        if (threadIdx.x == 0) out[0] = v / (float)BATCH;
    }
}

// ---------------------------------------------------------------------------
extern "C" void kernel_launch(void* const* d_in, const int* in_sizes, int n_in,
                              void* d_out, int out_size, void* d_ws, size_t ws_size,
                              hipStream_t stream)
{
    const float* emb    = (const float*)d_in[0];
    const int*   labels = (const int*)d_in[1];
    float*       out    = (float*)d_out;

    char* ws = (char*)d_ws;
    __hip_bfloat16* EbfA = (__hip_bfloat16*)ws;                       // 2.56 MiB
    __hip_bfloat16* EbfB = (__hip_bfloat16*)(ws + 3  * 1024 * 1024);  // 2.56 MiB
    float*    sq   = (float*)   (ws + 6 * 1024 * 1024);               // 32 KiB
    unsigned* hp2  = (unsigned*)(ws + 6 * 1024 * 1024 + 32 * 1024);   // 32 KiB
    unsigned* hn2  = (unsigned*)(ws + 6 * 1024 * 1024 + 64 * 1024);   // 32 KiB

    bhtl_prep<<<BATCH / 4, 256, 0, stream>>>(emb, labels, EbfA, EbfB, sq, hp2, hn2);
    bhtl_main<<<2080, 128, 0, stream>>>(EbfA, EbfB, sq, hp2, hn2);
    bhtl_final<<<1, 1024, 0, stream>>>(hp2, hn2, out);
}